// Round 11
// baseline (149.266 us; speedup 1.0000x reference)
//
#include <hip/hip_runtime.h>
#include <stdint.h>

// CausalSelfAttention: B=128 T=256 C=384 H=6 hd=64
// cvt(f32->bf16) -> GEMM1 qkv(+bias; q,k rows + V TRANSPOSED to vt) ->
// fused causal attention -> GEMM2 proj(+bias, f32)
// All matmuls via v_mfma_f32_16x16x32_bf16. Tolerance is bf16-floor (9.3e-2).

typedef unsigned short u16;
typedef __attribute__((ext_vector_type(8))) short short8;   // 8 bf16 (A/B frag)
typedef __attribute__((ext_vector_type(4))) short short4v;  // 4 bf16 (half frag)
typedef __attribute__((ext_vector_type(4))) float float4v;  // C/D frag

__device__ __forceinline__ u16 f2b(float f){            // f32 -> bf16 RNE
  union { float f; uint32_t u; } cv; cv.f = f;
  uint32_t u = cv.u;
  u += 0x7FFFu + ((u >> 16) & 1u);
  return (u16)(u >> 16);
}

__device__ __forceinline__ float4v mfma16(short8 a, short8 b, float4v c){
  return __builtin_amdgcn_mfma_f32_16x16x32_bf16(a, b, c, 0, 0, 0);
}

// async global->LDS, 16B per lane. LDS dest = wave-uniform base + lane*16.
__device__ __forceinline__ void gld16(const void* g, void* l){
  __builtin_amdgcn_global_load_lds((__attribute__((address_space(1))) const void*)g,
                                   (__attribute__((address_space(3))) void*)l, 16, 0, 0);
}

// ---------------------------------------------------------------------------
// Kernel 1: f32 -> bf16 conversion for x, w_attn, w_proj
// ---------------------------------------------------------------------------
__global__ __launch_bounds__(256) void cvt3(
    const float* __restrict__ a, u16* __restrict__ da, int na,
    const float* __restrict__ b, u16* __restrict__ db, int nb,
    const float* __restrict__ c, u16* __restrict__ dc, int nc)
{
  const int total = na + nb + nc;  // counts in float4 units
  for (int i = blockIdx.x * blockDim.x + threadIdx.x; i < total;
       i += gridDim.x * blockDim.x){
    const float* s; u16* d; int j = i;
    if (j < na)           { s = a; d = da; }
    else if (j < na + nb) { j -= na; s = b; d = db; }
    else                  { j -= na + nb; s = c; d = dc; }
    const float4 v = ((const float4*)s)[j];
    ushort4 o;
    o.x = f2b(v.x); o.y = f2b(v.y); o.z = f2b(v.z); o.w = f2b(v.w);
    ((ushort4*)d)[j] = o;
  }
}

// ---------------------------------------------------------------------------
// Kernel 2/4: bf16 GEMM  C[M,N] = A[M,K] * B[N,K]^T + bias, K=384 fixed.
// BARRIER-FREE K-LOOP: B panel (BN=64 x K=384 = 48KB) resident in LDS
// (staged once, XOR-granule swizzle: position p of row r holds source granule
// (p&~7)|((p^r)&7), an involution; reads use the same formula -> 2-way bank
// aliasing = free). A fragments load DIRECTLY global->VGPR: per wave instr
// 16 rows x 64B fully-consumed aligned lines (L1-perfect, L2-resident via
// XCD chunking). K-loop = 12 fully-unrolled steps, hand double-buffered
// (prefetch kt+1 while MFMA kt); NO barriers, NO inter-wave hazards ->
// compiler emits counted per-use waits; latency hidden by 2-deep prefetch
// + 2 blocks/CU (VGPR ~160, launch_bounds(256,2)).
// Block 256x64, 4 waves, wave tile 64x64 (acc[4][4]).
// EPI=1: bf16; col-tiles >=768 are V -> written TRANSPOSED to vt[b][h][d][t];
// q,k cols bounce through LDS (wave-private [64][72]) for 16B stores.
// EPI=0: f32 scalar stores (64B segments). CS = output row stride.
// Grid: 1-D XCD-chunked, yt-fastest.
// ---------------------------------------------------------------------------
template<int EPI>
__global__ __launch_bounds__(256, 2) void gemm_k(
    const u16* __restrict__ A, const u16* __restrict__ B,
    const float* __restrict__ bias, void* __restrict__ Cout,
    u16* __restrict__ Vt, const int M, const int N, const int CS)
{
  constexpr int K   = 384;
  constexpr int NKT = 12;
  __shared__ __align__(16) u16 Bl[64 * K];     // 48KB

  const int tid  = threadIdx.x;
  const int lane = tid & 63;
  const int wave = tid >> 6;
  const int lrow = lane & 15;
  const int g    = lane >> 4;

  // XCD-chunked decode, yt-fastest
  const int NYT   = N >> 6;
  const int xpx   = (M >> 8) >> 3;
  const int id    = blockIdx.x;
  const int local = id >> 3;
  const int xtl   = local / NYT;
  const int yt    = local - xtl * NYT;
  const int tm    = ((id & 7) * xpx + xtl) << 8;
  const int tn    = yt << 6;
  const int wm    = wave * 64;

  // ---- stage B panel once: load-all then swizzled ds_write-all
  {
    uint4 tmp[12];
    #pragma unroll
    for (int j = 0; j < 12; ++j){
      const int gi  = j * 256 + tid;           // granule 0..3071
      const int row = gi / 48;
      const int kg  = gi - row * 48;
      tmp[j] = *(const uint4*)(B + (size_t)(tn + row) * K + kg * 8);
    }
    #pragma unroll
    for (int j = 0; j < 12; ++j){
      const int gi  = j * 256 + tid;
      const int row = gi / 48;
      const int kg  = gi - row * 48;
      const int sk  = (kg & ~7) | ((kg ^ row) & 7);
      *(uint4*)&Bl[row * K + sk * 8] = tmp[j];
    }
  }

  float4v acc[4][4];
  #pragma unroll
  for (int i = 0; i < 4; ++i)
    #pragma unroll
    for (int j = 0; j < 4; ++j) acc[i][j] = (float4v){0.f, 0.f, 0.f, 0.f};

  const u16* a0 = A + (size_t)(tm + wm + lrow) * K + g * 8;  // wave A base

  __syncthreads();                             // B panel ready (only barrier)

  short8 afA[4], bfA[4], afB[4], bfB[4];
  #pragma unroll
  for (int i = 0; i < 4; ++i)
    afA[i] = *(const short8*)(a0 + i * 16 * K);
  #pragma unroll
  for (int ni = 0; ni < 4; ++ni){
    const int sk = (g & ~7) | ((g ^ lrow) & 7);              // kt=0: kg=g
    bfA[ni] = *(const short8*)&Bl[(ni * 16 + lrow) * K + sk * 8];
  }

  #pragma unroll
  for (int kt = 0; kt < NKT; ++kt){
    if ((kt & 1) == 0){
      if (kt + 1 < NKT){
        #pragma unroll
        for (int i = 0; i < 4; ++i)
          afB[i] = *(const short8*)(a0 + i * 16 * K + (kt + 1) * 32);
        #pragma unroll
        for (int ni = 0; ni < 4; ++ni){
          const int kg = (kt + 1) * 4 + g;
          const int sk = (kg & ~7) | ((kg ^ lrow) & 7);
          bfB[ni] = *(const short8*)&Bl[(ni * 16 + lrow) * K + sk * 8];
        }
      }
      #pragma unroll
      for (int ni = 0; ni < 4; ++ni)
        #pragma unroll
        for (int mi = 0; mi < 4; ++mi)
          acc[mi][ni] = mfma16(afA[mi], bfA[ni], acc[mi][ni]);
    } else {
      if (kt + 1 < NKT){
        #pragma unroll
        for (int i = 0; i < 4; ++i)
          afA[i] = *(const short8*)(a0 + i * 16 * K + (kt + 1) * 32);
        #pragma unroll
        for (int ni = 0; ni < 4; ++ni){
          const int kg = (kt + 1) * 4 + g;
          const int sk = (kg & ~7) | ((kg ^ lrow) & 7);
          bfA[ni] = *(const short8*)&Bl[(ni * 16 + lrow) * K + sk * 8];
        }
      }
      #pragma unroll
      for (int ni = 0; ni < 4; ++ni)
        #pragma unroll
        for (int mi = 0; mi < 4; ++mi)
          acc[mi][ni] = mfma16(afB[mi], bfB[ni], acc[mi][ni]);
    }
  }

  // ---- epilogue. D layout: col=lane&15, row=(lane>>4)*4+reg (HW-verified).
  __syncthreads();                             // all B reads done -> Bl reusable
  if (EPI == 1 && tn >= 768){
    // V third -> vt[b][h][d][t]; tm tile (256 rows) == one batch element
    const int bb = tm >> 8;
    #pragma unroll
    for (int ni = 0; ni < 4; ++ni){
      const int vcol0 = tn - 768 + ni * 16;
      const int hh = vcol0 >> 6;
      const int dd = (vcol0 & 63) + lrow;
      const float bs = bias[tn + ni * 16 + lrow];
      u16* vbase = Vt + ((size_t)(bb * 6 + hh) * 64 + dd) * 256;
      #pragma unroll
      for (int mi = 0; mi < 4; ++mi){
        #pragma unroll
        for (int r = 0; r < 4; ++r){
          const int t = wm + mi * 16 + g * 4 + r;
          vbase[t] = f2b(acc[mi][ni][r] + bs);
        }
      }
    }
  } else if (EPI == 1){
    // q,k cols: bounce via wave-private [64][72] u16 -> 16B coalesced stores
    u16* wreg = &Bl[wave * 4608];
    #pragma unroll
    for (int mi = 0; mi < 4; ++mi)
      #pragma unroll
      for (int ni = 0; ni < 4; ++ni){
        const float bs = bias[tn + ni * 16 + lrow];
        #pragma unroll
        for (int r = 0; r < 4; ++r)
          wreg[(mi * 16 + g * 4 + r) * 72 + ni * 16 + lrow] =
              f2b(acc[mi][ni][r] + bs);
      }
    asm volatile("s_waitcnt lgkmcnt(0)" ::: "memory");
    #pragma unroll
    for (int i = 0; i < 8; ++i){
      const int row = i * 8 + (lane >> 3);
      const short8 v = *(const short8*)&wreg[row * 72 + (lane & 7) * 8];
      *(short8*)((u16*)Cout + (size_t)(tm + wm + row) * CS + tn + (lane & 7) * 8) = v;
    }
  } else {
    // f32 scalar stores: 16 lanes x 4B = 64B segments, line-complete
    #pragma unroll
    for (int mi = 0; mi < 4; ++mi)
      #pragma unroll
      for (int ni = 0; ni < 4; ++ni){
        const float bs = bias[tn + ni * 16 + lrow];
        #pragma unroll
        for (int r = 0; r < 4; ++r){
          const int grow = tm + wm + mi * 16 + g * 4 + r;
          ((float*)Cout)[(size_t)grow * CS + tn + ni * 16 + lrow] =
              acc[mi][ni][r] + bs;
        }
      }
  }
}

// ---------------------------------------------------------------------------
// Kernel 3: fused causal attention, one workgroup per (b,h), 4 waves.
// Swapped QK^T (S^T = K*Q^T): softmax lane-local(+2 shfl), P feeds PV from
// registers. K in LDS (XOR row swizzle). V^T comes PRE-TRANSPOSED from GEMM1
// (vt[b][h][d][t]) -> staged via gld16 with 16B-unit XOR (unit u of row d at
// u^(d&7)); PV B-operand = two ds_read_b64 with the same (g,i)->t slot map.
// q-tile->wave map {w, 15-w, w+4, 11-w}: exactly 34 causal tiles per wave.
// ---------------------------------------------------------------------------
__global__ __launch_bounds__(256) void attn_k(
    const u16* __restrict__ qkv, const u16* __restrict__ vt,
    u16* __restrict__ y)
{
  __shared__ u16 Klds[256 * 64];   // K rows (128B), 16B granules XOR'd by row&7
  __shared__ u16 Vlds[64 * 256];   // V^T rows d (512B): unit u at u^(d&7)
  const int tid  = threadIdx.x;
  const int lane = tid & 63;
  const int wave = tid >> 6;
  const int lrow = lane & 15;
  const int g    = lane >> 4;
  const int bh = blockIdx.x;
  const int b = bh / 6, h = bh % 6;
  const u16* qb  = qkv + (size_t)b * 256 * 768 + h * 64;
  const u16* kb  = qb + 384;
  const u16* vtb = vt + (size_t)(b * 6 + h) * 64 * 256;

  // ---- stage K: elem K[t][c16*8+e] -> Klds[t*64 + (c16^(t&7))*8 + e]
  #pragma unroll
  for (int j = 0; j < 8; ++j){
    const int c = wave * 8 + j;                 // 1KB chunk = 8 K-rows
    const int row = c * 8 + (lane >> 3);
    const int col = (((lane & 7) ^ (lane >> 3)) << 3);
    gld16(kb + (size_t)row * 768 + col, &Klds[c * 512]);
  }
  // ---- stage V^T: chunk c = rows {2c,2c+1}; LDS unit q of row d <- src q^(d&7)
  #pragma unroll
  for (int j = 0; j < 8; ++j){
    const int c  = wave * 8 + j;
    const int dd = c * 2 + (lane >> 5);
    const int q  = lane & 31;
    gld16(vtb + (size_t)dd * 256 + ((q ^ (dd & 7)) << 3), &Vlds[c * 512]);
  }
  __syncthreads();

  #pragma unroll
  for (int it = 0; it < 4; ++it){
    const int rb = (it == 0) ? wave : (it == 1) ? 15 - wave
                 : (it == 2) ? wave + 4 : 11 - wave;
    const int q0 = rb * 16;
    const u16* qrow = qb + (size_t)(q0 + lrow) * 768 + g * 8;
    const short8 qf0 = *(const short8*)(qrow);
    const short8 qf1 = *(const short8*)(qrow + 32);

    // S^T[t][q]: lane holds t = nt*16 + g*4 + r for its q = q0 + lrow
    float4v s[16];
    #pragma unroll
    for (int nt = 0; nt < 16; ++nt){
      if (nt <= rb){
        const int row = nt * 16 + lrow;    // K row (A operand m = lane&15)
        const int swk = lrow & 7;
        const short8 k0 = *(const short8*)&Klds[row * 64 + ((g ^ swk) << 3)];
        const short8 k1 = *(const short8*)&Klds[row * 64 + (((4 + g) ^ swk) << 3)];
        float4v a = (float4v){0.f, 0.f, 0.f, 0.f};
        a = mfma16(k0, qf0, a);
        a = mfma16(k1, qf1, a);
        if (nt == rb){                     // diagonal tile mask: t > q
          #pragma unroll
          for (int r = 0; r < 4; ++r)
            a[r] = (g * 4 + r > lrow) ? -1e30f : a[r];
        }
        s[nt] = a;
      }
    }

    // softmax over t for fixed q: lane-local + reduce across the 4 lane-groups
    float mx = -1e30f;
    #pragma unroll
    for (int nt = 0; nt < 16; ++nt) if (nt <= rb){
      #pragma unroll
      for (int r = 0; r < 4; ++r) mx = fmaxf(mx, s[nt][r]);
    }
    mx = fmaxf(mx, __shfl_xor(mx, 16));
    mx = fmaxf(mx, __shfl_xor(mx, 32));
    float sum = 0.f;
    #pragma unroll
    for (int nt = 0; nt < 16; ++nt) if (nt <= rb){
      #pragma unroll
      for (int r = 0; r < 4; ++r){
        const float p = exp2f((s[nt][r] - mx) * 0.18033688011112042f);
        s[nt][r] = p;
        sum += p;
      }
    }
    sum += __shfl_xor(sum, 16);
    sum += __shfl_xor(sum, 32);
    const float rs = 1.f / sum;
    #pragma unroll
    for (int nt = 0; nt < 16; ++nt) if (nt <= rb) s[nt] *= rs;

    // PV: O[q][d] += P[q][t] V[t][d]; slot map (both operands):
    //   i<4 -> t=kt*32+g*4+i ; i>=4 -> t=kt*32+16+g*4+(i-4)
    float4v o0 = (float4v){0,0,0,0}, o1 = (float4v){0,0,0,0};
    float4v o2 = (float4v){0,0,0,0}, o3 = (float4v){0,0,0,0};
    const int swk = lrow & 7;
    #pragma unroll
    for (int kt = 0; kt < 8; ++kt){
      if (2 * kt <= rb){
        short8 pa;
        #pragma unroll
        for (int r = 0; r < 4; ++r) pa[r] = (short)f2b(s[2 * kt][r]);
        if (2 * kt + 1 <= rb){
          #pragma unroll
          for (int r = 0; r < 4; ++r) pa[4 + r] = (short)f2b(s[2 * kt + 1][r]);
        } else {
          #pragma unroll
          for (int r = 0; r < 4; ++r) pa[4 + r] = 0;
        }
        // granule p of row d at elems: d*256 + ((p>>1)^(d&7))*8 + (p&1)*4
        const int plo_e = (((kt * 4 +     (g >> 1)) ^ swk) << 3) + ((g & 1) << 2);
        const int phi_e = (((kt * 4 + 2 + (g >> 1)) ^ swk) << 3) + ((g & 1) << 2);
        #pragma unroll
        for (int dt = 0; dt < 4; ++dt){
          const u16* vrow = &Vlds[(size_t)(dt * 16 + lrow) * 256];
          const short4v vlo = *(const short4v*)&vrow[plo_e];
          const short4v vhi = *(const short4v*)&vrow[phi_e];
          const short8 bf = __builtin_shufflevector(vlo, vhi, 0,1,2,3,4,5,6,7);
          if      (dt == 0) o0 = mfma16(pa, bf, o0);
          else if (dt == 1) o1 = mfma16(pa, bf, o1);
          else if (dt == 2) o2 = mfma16(pa, bf, o2);
          else              o3 = mfma16(pa, bf, o3);
        }
      }
    }

    // write O: D row=(g*4+r) -> q-within-tile, col=lrow -> d within 16-tile
    u16* yb = y + (size_t)(b * 256 + q0) * 384 + h * 64;
    #pragma unroll
    for (int r = 0; r < 4; ++r){
      const int q = g * 4 + r;
      yb[(size_t)q * 384 +  0 + lrow] = f2b(o0[r]);
      yb[(size_t)q * 384 + 16 + lrow] = f2b(o1[r]);
      yb[(size_t)q * 384 + 32 + lrow] = f2b(o2[r]);
      yb[(size_t)q * 384 + 48 + lrow] = f2b(o3[r]);
    }
  }
}

// ---------------------------------------------------------------------------
extern "C" void kernel_launch(void* const* d_in, const int* in_sizes, int n_in,
                              void* d_out, int out_size, void* d_ws, size_t ws_size,
                              hipStream_t stream)
{
  const float* x      = (const float*)d_in[0];
  const float* w_attn = (const float*)d_in[1];
  const float* b_attn = (const float*)d_in[2];
  const float* w_proj = (const float*)d_in[3];
  const float* b_proj = (const float*)d_in[4];
  float* out = (float*)d_out;

  // workspace layout (bytes)
  char* ws = (char*)d_ws;
  u16* xb  = (u16*)(ws);                 // 25,165,824  x bf16 [32768,384]
  u16* wab = (u16*)(ws + 25165824);      //    884,736  w_attn bf16 [1152,384]
  u16* wpb = (u16*)(ws + 26050560);      //    294,912  w_proj bf16 [384,384]
  u16* qkv = (u16*)(ws + 26345472);      // 50,331,648  q,k bf16 [32768,768]
  u16* vt  = (u16*)(ws + 76677120);      // 25,165,824  V^T bf16 [128][6][64][256]
  u16* yb  = (u16*)(ws + 101842944);     // 25,165,824  attn out bf16 [32768,384]
  if (ws_size < 127008768) return;

  cvt3<<<2048, 256, 0, stream>>>(x, xb, 3145728,
                                 w_attn, wab, 110592,
                                 w_proj, wpb, 36864);
  // GEMM1: 128 M-tiles(256) x 18 N-tiles(64) = 2304 blocks (XCD-chunked)
  gemm_k<1><<<2304, 256, 0, stream>>>(xb, wab, b_attn, qkv, vt, 32768, 1152, 768);
  attn_k<<<768, 256, 0, stream>>>(qkv, vt, yb);
  // GEMM2: 128 M-tiles(256) x 6 N-tiles(64) = 768 blocks
  gemm_k<0><<<768, 256, 0, stream>>>(yb, wpb, b_proj, out, nullptr, 32768, 384, 384);
}

// Round 12
// 128.028 us; speedup vs baseline: 1.1659x; 1.1659x over previous
//
#include <hip/hip_runtime.h>
#include <stdint.h>

// CausalSelfAttention: B=128 T=256 C=384 H=6 hd=64
// cvt(f32->bf16) -> GEMM1 qkv(+bias; q,k rows + V TRANSPOSED to vt) ->
// fused causal attention -> GEMM2 proj(+bias, f32)
// All matmuls via v_mfma_f32_16x16x32_bf16. Tolerance is bf16-floor (9.3e-2).

typedef unsigned short u16;
typedef __attribute__((ext_vector_type(8))) short short8;   // 8 bf16 (A/B frag)
typedef __attribute__((ext_vector_type(4))) short short4v;  // 4 bf16 (half frag)
typedef __attribute__((ext_vector_type(4))) float float4v;  // C/D frag

__device__ __forceinline__ u16 f2b(float f){            // f32 -> bf16 RNE
  union { float f; uint32_t u; } cv; cv.f = f;
  uint32_t u = cv.u;
  u += 0x7FFFu + ((u >> 16) & 1u);
  return (u16)(u >> 16);
}

__device__ __forceinline__ float4v mfma16(short8 a, short8 b, float4v c){
  return __builtin_amdgcn_mfma_f32_16x16x32_bf16(a, b, c, 0, 0, 0);
}

// async global->LDS, 16B per lane. LDS dest = wave-uniform base + lane*16.
__device__ __forceinline__ void gld16(const void* g, void* l){
  __builtin_amdgcn_global_load_lds((__attribute__((address_space(1))) const void*)g,
                                   (__attribute__((address_space(3))) void*)l, 16, 0, 0);
}

// ---------------------------------------------------------------------------
// Kernel 1: f32 -> bf16 conversion for x, w_attn, w_proj
// ---------------------------------------------------------------------------
__global__ __launch_bounds__(256) void cvt3(
    const float* __restrict__ a, u16* __restrict__ da, int na,
    const float* __restrict__ b, u16* __restrict__ db, int nb,
    const float* __restrict__ c, u16* __restrict__ dc, int nc)
{
  const int total = na + nb + nc;  // counts in float4 units
  for (int i = blockIdx.x * blockDim.x + threadIdx.x; i < total;
       i += gridDim.x * blockDim.x){
    const float* s; u16* d; int j = i;
    if (j < na)           { s = a; d = da; }
    else if (j < na + nb) { j -= na; s = b; d = db; }
    else                  { j -= na + nb; s = c; d = dc; }
    const float4 v = ((const float4*)s)[j];
    ushort4 o;
    o.x = f2b(v.x); o.y = f2b(v.y); o.z = f2b(v.z); o.w = f2b(v.w);
    ((ushort4*)d)[j] = o;
  }
}

// ---------------------------------------------------------------------------
// Kernel 2/4: bf16 GEMM  C[M,N] = A[M,K] * B[N,K]^T + bias, K=384 fixed.
// m201-style phase schedule. Tile 256x128, BK=64, 512 threads (8 waves,
// 4Mx2N, wave 64x64, acc[4][4]). LDS 128KB: A 3-buffered (32KB ea, 2-tile
// lookahead) + B 2-buffered (16KB ea, 1-tile).
// Per tile t (buffers ab=t%3, bb=t&1):
//   vmcnt(4) ; s_barrier            // A(t),B(t) landed; A(t+2) stays in flight
//   STAGE_B(t+1) ; STAGE_A(t+2)     // issue-first: ~2 phases before waited
//   phase kk=0: ds_read 4A+4B ; s_barrier ; lgkm0+sched_barrier ;
//               setprio(1) 16 MFMA setprio(0) ; s_barrier
//   phase kk=1: same with kg=4+g granules (no stage)
// vmcnt(4) accounting (FIFO, issue order B-then-A): at tile-t start the queue
// is [A(t+1)(4), B(t)(2), A(t+2)... wait->] steady state: retire A(t),B(t),
// leave A(t+1)'s 4. Prologue: A0,A1,B0 + vmcnt(0). Tail guards for t+1,t+2.
// Swizzle (R3-measured 0-conflict): 16B granule kg of row r at kg^(r&7),
// carried on the gld16 SOURCE address; frag reads use the same XOR.
// EPI=1: bf16; tn>=768 is V -> written TRANSPOSED to vt[b][h][d][t];
// else bounce via wave-private LDS -> 16B stores. EPI=0: f32 scalar stores.
// Grid: 1-D XCD-chunked, yt-fastest.
// ---------------------------------------------------------------------------
template<int EPI>
__global__ __launch_bounds__(512, 1) void gemm8(
    const u16* __restrict__ A, const u16* __restrict__ B,
    const float* __restrict__ bias, void* __restrict__ Cout,
    u16* __restrict__ Vt, const int M, const int N, const int CS)
{
  constexpr int K    = 384;
  constexpr int NKT  = 6;                      // K / 64
  constexpr int ABUF = 16384;                  // u16 per A buffer (256x64)
  constexpr int ATOT = 3 * ABUF;               // 49152
  constexpr int BBUF = 8192;                   // u16 per B buffer (128x64)
  __shared__ __align__(16) u16 SH[ATOT + 2 * BBUF];   // 131072 B = 128KB

  const int tid  = threadIdx.x;
  const int lane = tid & 63;
  const int wave = tid >> 6;
  const int lrow = lane & 15;
  const int g    = lane >> 4;

  // XCD-chunked decode, yt-fastest
  const int NYT   = N >> 7;
  const int id    = blockIdx.x;
  const int local = id >> 3;
  const int xtl   = local / NYT;
  const int yt    = local - xtl * NYT;
  const int tm    = ((id & 7) * 16 + xtl) << 8;
  const int tn    = yt << 7;
  const int wm    = (wave >> 1) * 64;
  const int wn    = (wave & 1) * 64;

  float4v acc[4][4];
  #pragma unroll
  for (int i = 0; i < 4; ++i)
    #pragma unroll
    for (int j = 0; j < 4; ++j) acc[i][j] = (float4v){0.f, 0.f, 0.f, 0.f};

  // staging: chunk = 8 rows x 64 cols (1KB); lane l -> row l>>3, LDS pos l&7;
  // source granule = (l&7)^(l>>3) so LDS pos p of row r holds src granule p^(r&7)
  const int srw = lane >> 3;
  const int sg  = ((lane & 7) ^ (lane >> 3)) << 3;   // src granule offset (elems)
  const int key = lrow & 7;                          // frag-read swizzle key

  auto STAGE_A = [&](int kt, int buf){               // 4 gld16 (32 chunks/8 waves)
    #pragma unroll
    for (int j = 0; j < 4; ++j){
      const int c = wave * 4 + j;
      const int row = c * 8 + srw;
      gld16(A + (size_t)(tm + row) * K + kt * 64 + sg, &SH[buf * ABUF + c * 512]);
    }
  };
  auto STAGE_B = [&](int kt, int buf){               // 2 gld16 (16 chunks/8 waves)
    #pragma unroll
    for (int j = 0; j < 2; ++j){
      const int c = wave * 2 + j;
      const int row = c * 8 + srw;
      gld16(B + (size_t)(tn + row) * K + kt * 64 + sg, &SH[ATOT + buf * BBUF + c * 512]);
    }
  };

  // prologue: A(0), A(1), B(0); drain once (allowed outside the loop)
  STAGE_A(0, 0);
  STAGE_A(1, 1);
  STAGE_B(0, 0);
  asm volatile("s_waitcnt vmcnt(0)" ::: "memory");
  __builtin_amdgcn_s_barrier();
  __builtin_amdgcn_sched_barrier(0);

  for (int kt = 0; kt < NKT; ++kt){
    const int ab = kt % 3, bb = kt & 1;
    if (kt > 0){
      // steady state: retire A(kt)+B(kt); A(kt+1) [4 loads] stays in flight
      if (kt + 1 < NKT) asm volatile("s_waitcnt vmcnt(4)" ::: "memory");
      else              asm volatile("s_waitcnt vmcnt(0)" ::: "memory");
      __builtin_amdgcn_s_barrier();
      __builtin_amdgcn_sched_barrier(0);
    }
    // issue next stages first (B before A: FIFO makes vmcnt(4) retire B(t+1) next tile)
    if (kt + 1 < NKT) STAGE_B(kt + 1, bb ^ 1);
    if (kt + 2 < NKT) STAGE_A(kt + 2, (kt + 2) % 3);

    #pragma unroll
    for (int kk = 0; kk < 2; ++kk){
      short8 af[4], bf[4];
      #pragma unroll
      for (int i = 0; i < 4; ++i)
        af[i] = *(const short8*)&SH[ab * ABUF + (wm + i * 16 + lrow) * 64
                                    + (((kk * 4 + g) ^ key) << 3)];
      #pragma unroll
      for (int ni = 0; ni < 4; ++ni)
        bf[ni] = *(const short8*)&SH[ATOT + bb * BBUF + (wn + ni * 16 + lrow) * 64
                                     + (((kk * 4 + g) ^ key) << 3)];
      __builtin_amdgcn_s_barrier();
      asm volatile("s_waitcnt lgkmcnt(0)" ::: "memory");
      __builtin_amdgcn_sched_barrier(0);             // rule 18: MFMA stays below
      __builtin_amdgcn_s_setprio(1);
      #pragma unroll
      for (int ni = 0; ni < 4; ++ni)
        #pragma unroll
        for (int mi = 0; mi < 4; ++mi)
          acc[mi][ni] = mfma16(af[mi], bf[ni], acc[mi][ni]);
      __builtin_amdgcn_s_setprio(0);
      if (kk == 0) __builtin_amdgcn_s_barrier();     // phase boundary
    }
  }

  __syncthreads();                                   // all LDS frag reads done
  // ---- epilogue. D layout: col=lane&15, row=(lane>>4)*4+reg (HW-verified).
  if (EPI == 1 && tn >= 768){
    // V third -> vt[b][h][d][t]; tm tile (256 rows) == one batch element
    const int bb2 = tm >> 8;
    #pragma unroll
    for (int ni = 0; ni < 4; ++ni){
      const int vcol0 = tn + wn - 768 + ni * 16;
      const int hh = vcol0 >> 6;
      const int dd = (vcol0 & 63) + lrow;
      const float bs = bias[tn + wn + ni * 16 + lrow];
      u16* vbase = Vt + ((size_t)(bb2 * 6 + hh) * 64 + dd) * 256;
      #pragma unroll
      for (int mi = 0; mi < 4; ++mi){
        #pragma unroll
        for (int r = 0; r < 4; ++r){
          const int t = wm + mi * 16 + g * 4 + r;
          vbase[t] = f2b(acc[mi][ni][r] + bs);
        }
      }
    }
  } else if (EPI == 1){
    // q,k cols: bounce via wave-private [64][72] u16 -> 16B coalesced stores
    u16* wreg = &SH[wave * 4608];
    #pragma unroll
    for (int mi = 0; mi < 4; ++mi)
      #pragma unroll
      for (int ni = 0; ni < 4; ++ni){
        const float bs = bias[tn + wn + ni * 16 + lrow];
        #pragma unroll
        for (int r = 0; r < 4; ++r)
          wreg[(mi * 16 + g * 4 + r) * 72 + ni * 16 + lrow] =
              f2b(acc[mi][ni][r] + bs);
      }
    asm volatile("s_waitcnt lgkmcnt(0)" ::: "memory");
    #pragma unroll
    for (int i = 0; i < 8; ++i){
      const int row = i * 8 + (lane >> 3);
      const short8 v = *(const short8*)&wreg[row * 72 + (lane & 7) * 8];
      *(short8*)((u16*)Cout + (size_t)(tm + wm + row) * CS + tn + wn + (lane & 7) * 8) = v;
    }
  } else {
    // f32 scalar stores: 16 lanes x 4B = 64B segments, line-complete
    #pragma unroll
    for (int mi = 0; mi < 4; ++mi)
      #pragma unroll
      for (int ni = 0; ni < 4; ++ni){
        const float bs = bias[tn + wn + ni * 16 + lrow];
        #pragma unroll
        for (int r = 0; r < 4; ++r){
          const int grow = tm + wm + mi * 16 + g * 4 + r;
          ((float*)Cout)[(size_t)grow * CS + tn + wn + ni * 16 + lrow] =
              acc[mi][ni][r] + bs;
        }
      }
  }
}

// ---------------------------------------------------------------------------
// Kernel 3: fused causal attention, one workgroup per (b,h), 4 waves.
// Swapped QK^T (S^T = K*Q^T): softmax lane-local(+2 shfl), P feeds PV from
// registers. K in LDS (XOR row swizzle). V^T comes PRE-TRANSPOSED from GEMM1
// (vt[b][h][d][t]) -> staged via gld16 with 16B-unit XOR (unit u of row d at
// u^(d&7)); PV B-operand = two ds_read_b64 with the same (g,i)->t slot map.
// q-tile->wave map {w, 15-w, w+4, 11-w}: exactly 34 causal tiles per wave.
// ---------------------------------------------------------------------------
__global__ __launch_bounds__(256) void attn_k(
    const u16* __restrict__ qkv, const u16* __restrict__ vt,
    u16* __restrict__ y)
{
  __shared__ u16 Klds[256 * 64];   // K rows (128B), 16B granules XOR'd by row&7
  __shared__ u16 Vlds[64 * 256];   // V^T rows d (512B): unit u at u^(d&7)
  const int tid  = threadIdx.x;
  const int lane = tid & 63;
  const int wave = tid >> 6;
  const int lrow = lane & 15;
  const int g    = lane >> 4;
  const int bh = blockIdx.x;
  const int b = bh / 6, h = bh % 6;
  const u16* qb  = qkv + (size_t)b * 256 * 768 + h * 64;
  const u16* kb  = qb + 384;
  const u16* vtb = vt + (size_t)(b * 6 + h) * 64 * 256;

  // ---- stage K: elem K[t][c16*8+e] -> Klds[t*64 + (c16^(t&7))*8 + e]
  #pragma unroll
  for (int j = 0; j < 8; ++j){
    const int c = wave * 8 + j;                 // 1KB chunk = 8 K-rows
    const int row = c * 8 + (lane >> 3);
    const int col = (((lane & 7) ^ (lane >> 3)) << 3);
    gld16(kb + (size_t)row * 768 + col, &Klds[c * 512]);
  }
  // ---- stage V^T: chunk c = rows {2c,2c+1}; LDS unit q of row d <- src q^(d&7)
  #pragma unroll
  for (int j = 0; j < 8; ++j){
    const int c  = wave * 8 + j;
    const int dd = c * 2 + (lane >> 5);
    const int q  = lane & 31;
    gld16(vtb + (size_t)dd * 256 + ((q ^ (dd & 7)) << 3), &Vlds[c * 512]);
  }
  __syncthreads();

  #pragma unroll
  for (int it = 0; it < 4; ++it){
    const int rb = (it == 0) ? wave : (it == 1) ? 15 - wave
                 : (it == 2) ? wave + 4 : 11 - wave;
    const int q0 = rb * 16;
    const u16* qrow = qb + (size_t)(q0 + lrow) * 768 + g * 8;
    const short8 qf0 = *(const short8*)(qrow);
    const short8 qf1 = *(const short8*)(qrow + 32);

    // S^T[t][q]: lane holds t = nt*16 + g*4 + r for its q = q0 + lrow
    float4v s[16];
    #pragma unroll
    for (int nt = 0; nt < 16; ++nt){
      if (nt <= rb){
        const int row = nt * 16 + lrow;    // K row (A operand m = lane&15)
        const int swk = lrow & 7;
        const short8 k0 = *(const short8*)&Klds[row * 64 + ((g ^ swk) << 3)];
        const short8 k1 = *(const short8*)&Klds[row * 64 + (((4 + g) ^ swk) << 3)];
        float4v a = (float4v){0.f, 0.f, 0.f, 0.f};
        a = mfma16(k0, qf0, a);
        a = mfma16(k1, qf1, a);
        if (nt == rb){                     // diagonal tile mask: t > q
          #pragma unroll
          for (int r = 0; r < 4; ++r)
            a[r] = (g * 4 + r > lrow) ? -1e30f : a[r];
        }
        s[nt] = a;
      }
    }

    // softmax over t for fixed q: lane-local + reduce across the 4 lane-groups
    float mx = -1e30f;
    #pragma unroll
    for (int nt = 0; nt < 16; ++nt) if (nt <= rb){
      #pragma unroll
      for (int r = 0; r < 4; ++r) mx = fmaxf(mx, s[nt][r]);
    }
    mx = fmaxf(mx, __shfl_xor(mx, 16));
    mx = fmaxf(mx, __shfl_xor(mx, 32));
    float sum = 0.f;
    #pragma unroll
    for (int nt = 0; nt < 16; ++nt) if (nt <= rb){
      #pragma unroll
      for (int r = 0; r < 4; ++r){
        const float p = exp2f((s[nt][r] - mx) * 0.18033688011112042f);
        s[nt][r] = p;
        sum += p;
      }
    }
    sum += __shfl_xor(sum, 16);
    sum += __shfl_xor(sum, 32);
    const float rs = 1.f / sum;
    #pragma unroll
    for (int nt = 0; nt < 16; ++nt) if (nt <= rb) s[nt] *= rs;

    // PV: O[q][d] += P[q][t] V[t][d]; slot map (both operands):
    //   i<4 -> t=kt*32+g*4+i ; i>=4 -> t=kt*32+16+g*4+(i-4)
    float4v o0 = (float4v){0,0,0,0}, o1 = (float4v){0,0,0,0};
    float4v o2 = (float4v){0,0,0,0}, o3 = (float4v){0,0,0,0};
    const int swk = lrow & 7;
    #pragma unroll
    for (int kt = 0; kt < 8; ++kt){
      if (2 * kt <= rb){
        short8 pa;
        #pragma unroll
        for (int r = 0; r < 4; ++r) pa[r] = (short)f2b(s[2 * kt][r]);
        if (2 * kt + 1 <= rb){
          #pragma unroll
          for (int r = 0; r < 4; ++r) pa[4 + r] = (short)f2b(s[2 * kt + 1][r]);
        } else {
          #pragma unroll
          for (int r = 0; r < 4; ++r) pa[4 + r] = 0;
        }
        // granule p of row d at elems: d*256 + ((p>>1)^(d&7))*8 + (p&1)*4
        const int plo_e = (((kt * 4 +     (g >> 1)) ^ swk) << 3) + ((g & 1) << 2);
        const int phi_e = (((kt * 4 + 2 + (g >> 1)) ^ swk) << 3) + ((g & 1) << 2);
        #pragma unroll
        for (int dt = 0; dt < 4; ++dt){
          const u16* vrow = &Vlds[(size_t)(dt * 16 + lrow) * 256];
          const short4v vlo = *(const short4v*)&vrow[plo_e];
          const short4v vhi = *(const short4v*)&vrow[phi_e];
          const short8 bf = __builtin_shufflevector(vlo, vhi, 0,1,2,3,4,5,6,7);
          if      (dt == 0) o0 = mfma16(pa, bf, o0);
          else if (dt == 1) o1 = mfma16(pa, bf, o1);
          else if (dt == 2) o2 = mfma16(pa, bf, o2);
          else              o3 = mfma16(pa, bf, o3);
        }
      }
    }

    // write O: D row=(g*4+r) -> q-within-tile, col=lrow -> d within 16-tile
    u16* yb = y + (size_t)(b * 256 + q0) * 384 + h * 64;
    #pragma unroll
    for (int r = 0; r < 4; ++r){
      const int q = g * 4 + r;
      yb[(size_t)q * 384 +  0 + lrow] = f2b(o0[r]);
      yb[(size_t)q * 384 + 16 + lrow] = f2b(o1[r]);
      yb[(size_t)q * 384 + 32 + lrow] = f2b(o2[r]);
      yb[(size_t)q * 384 + 48 + lrow] = f2b(o3[r]);
    }
  }
}

// ---------------------------------------------------------------------------
extern "C" void kernel_launch(void* const* d_in, const int* in_sizes, int n_in,
                              void* d_out, int out_size, void* d_ws, size_t ws_size,
                              hipStream_t stream)
{
  const float* x      = (const float*)d_in[0];
  const float* w_attn = (const float*)d_in[1];
  const float* b_attn = (const float*)d_in[2];
  const float* w_proj = (const float*)d_in[3];
  const float* b_proj = (const float*)d_in[4];
  float* out = (float*)d_out;

  // workspace layout (bytes)
  char* ws = (char*)d_ws;
  u16* xb  = (u16*)(ws);                 // 25,165,824  x bf16 [32768,384]
  u16* wab = (u16*)(ws + 25165824);      //    884,736  w_attn bf16 [1152,384]
  u16* wpb = (u16*)(ws + 26050560);      //    294,912  w_proj bf16 [384,384]
  u16* qkv = (u16*)(ws + 26345472);      // 50,331,648  q,k bf16 [32768,768]
  u16* vt  = (u16*)(ws + 76677120);      // 25,165,824  V^T bf16 [128][6][64][256]
  u16* yb  = (u16*)(ws + 101842944);     // 25,165,824  attn out bf16 [32768,384]
  if (ws_size < 127008768) return;

  cvt3<<<2048, 256, 0, stream>>>(x, xb, 3145728,
                                 w_attn, wab, 110592,
                                 w_proj, wpb, 36864);
  // GEMM1: 128 M-tiles(256) x 9 N-tiles(128) = 1152 blocks (XCD-chunked)
  gemm8<1><<<1152, 512, 0, stream>>>(xb, wab, b_attn, qkv, vt, 32768, 1152, 768);
  attn_k<<<768, 256, 0, stream>>>(qkv, vt, yb);
  // GEMM2: 128 M-tiles(256) x 3 N-tiles(128) = 384 blocks
  gemm8<0><<<384, 512, 0, stream>>>(yb, wpb, b_proj, out, nullptr, 32768, 384, 384);
}

// Round 14
// 117.325 us; speedup vs baseline: 1.2722x; 1.0912x over previous
//
#include <hip/hip_runtime.h>
#include <stdint.h>

// CausalSelfAttention: B=128 T=256 C=384 H=6 hd=64
// cvt(f32->bf16) -> GEMM1 qkv(+bias; q,k rows + V TRANSPOSED to vt) ->
// fused causal attention -> GEMM2 proj(+bias, f32)
// All matmuls via v_mfma_f32_16x16x32_bf16. Tolerance is bf16-floor (9.3e-2).

typedef unsigned short u16;
typedef __attribute__((ext_vector_type(8))) short short8;   // 8 bf16 (A/B frag)
typedef __attribute__((ext_vector_type(4))) short short4v;  // 4 bf16 (half frag)
typedef __attribute__((ext_vector_type(4))) float float4v;  // C/D frag

__device__ __forceinline__ u16 f2b(float f){            // f32 -> bf16 RNE
  union { float f; uint32_t u; } cv; cv.f = f;
  uint32_t u = cv.u;
  u += 0x7FFFu + ((u >> 16) & 1u);
  return (u16)(u >> 16);
}

__device__ __forceinline__ u16 f2b_t(float f){          // f32 -> bf16 truncate (1 op)
  union { float f; uint32_t u; } cv; cv.f = f;
  return (u16)(cv.u >> 16);
}

__device__ __forceinline__ float4v mfma16(short8 a, short8 b, float4v c){
  return __builtin_amdgcn_mfma_f32_16x16x32_bf16(a, b, c, 0, 0, 0);
}

// async global->LDS, 16B per lane. LDS dest = wave-uniform base + lane*16.
__device__ __forceinline__ void gld16(const void* g, void* l){
  __builtin_amdgcn_global_load_lds((__attribute__((address_space(1))) const void*)g,
                                   (__attribute__((address_space(3))) void*)l, 16, 0, 0);
}

// ---------------------------------------------------------------------------
// Kernel 1: f32 -> bf16 conversion for x, w_attn, w_proj
// ---------------------------------------------------------------------------
__global__ __launch_bounds__(256) void cvt3(
    const float* __restrict__ a, u16* __restrict__ da, int na,
    const float* __restrict__ b, u16* __restrict__ db, int nb,
    const float* __restrict__ c, u16* __restrict__ dc, int nc)
{
  const int total = na + nb + nc;  // counts in float4 units
  for (int i = blockIdx.x * blockDim.x + threadIdx.x; i < total;
       i += gridDim.x * blockDim.x){
    const float* s; u16* d; int j = i;
    if (j < na)           { s = a; d = da; }
    else if (j < na + nb) { j -= na; s = b; d = db; }
    else                  { j -= na + nb; s = c; d = dc; }
    const float4 v = ((const float4*)s)[j];
    ushort4 o;
    o.x = f2b(v.x); o.y = f2b(v.y); o.z = f2b(v.z); o.w = f2b(v.w);
    ((ushort4*)d)[j] = o;
  }
}

// ---------------------------------------------------------------------------
// Kernel 2/4: bf16 GEMM  C[M,N] = A[M,K] * B[N,K]^T + bias  (nn.Linear layout)
// R6 champion pipeline (50.9us GEMM1 measured): BK=32, 4 waves, 3 LDS buffers,
// counted vmcnt, TWO raw barriers per K-step:
//   tile t: vmcnt(L)->B1 ; frag ds_reads ; lgkm(0)->B2 ; STAGE(t+2) ; MFMA
// BM=256: wave tile 64x128 (acc[4][8]), LDS 72KB -> 2 blocks/CU  [GEMM1]
// BM=128: wave tile 64x64  (acc[4][4]), LDS 48KB -> 3 blocks/CU  [GEMM2]
// Scalar-store epilogues (R10's LDS bounce measured SLOWER). EPI=1: bf16 out;
// col-tiles >=768 are V -> written TRANSPOSED to vt[b][h][d][t]. EPI=0: f32.
// Grid: 1-D XCD-chunked, yt-fastest (A-panel per XCD ~3MB < 4MB L2).
// No pointer-arrays into LDS (gfx950 addrspacecast static-init bug).
// ---------------------------------------------------------------------------
template<int BM, int EPI>
__global__ __launch_bounds__(256, 2) void gemm_k(
    const u16* __restrict__ A, const u16* __restrict__ B,
    const float* __restrict__ bias, void* __restrict__ Cout,
    u16* __restrict__ Vt, const int M, const int N, const int K, const int CS)
{
  constexpr int NN    = (BM == 256) ? 8 : 4;   // ni count (wave cols / 16)
  constexpr int AB    = BM * 32;               // u16 per A buffer
  constexpr int ACH   = BM / 64;               // A chunks per wave (4 or 2)
  constexpr int BOFF  = 3 * AB;                // B buffers start (u16)
  constexpr int SHSZ  = 3 * AB + 3 * 4096;     // 72KB (BM=256) / 48KB (BM=128)
  __shared__ __align__(16) u16 SH[SHSZ];

  const int tid  = threadIdx.x;
  const int lane = tid & 63;
  const int wave = tid >> 6;
  const int lrow = lane & 15;
  const int g    = lane >> 4;

  // XCD-chunked decode, yt-fastest
  const int NYT   = N >> 7;
  const int xpx   = (M / BM) >> 3;             // x-tiles per XCD
  const int id    = blockIdx.x;
  const int local = id >> 3;
  const int xtl   = local / NYT;
  const int yt    = local - xtl * NYT;
  const int tm = ((id & 7) * xpx + xtl) * BM;
  const int tn = yt * 128;
  const int wm = (BM == 256) ? wave * 64 : (wave >> 1) * 64;
  const int wn = (BM == 256) ? 0          : (wave & 1) * 64;

  float4v acc[4][NN];
  #pragma unroll
  for (int i = 0; i < 4; ++i)
    #pragma unroll
    for (int j = 0; j < NN; ++j) acc[i][j] = (float4v){0.f, 0.f, 0.f, 0.f};

  // staging: chunk c (1KB) = 16 rows x 32 cols; LDS granule q of row r holds
  // source granule q ^ ((r>>1)&3)  (R3/R6-verified conflict-free pattern)
  const int srow = lane >> 2;
  const int sg   = ((lane & 3) ^ ((lane >> 3) & 3)) << 3;
  const int key  = (lrow >> 1) & 3;

  auto STAGE = [&](int kt, int buf){
    #pragma unroll
    for (int j = 0; j < ACH; ++j){               // A chunks
      const int c = wave * ACH + j;
      const int row = c * 16 + srow;
      gld16(A + (size_t)(tm + row) * K + kt * 32 + sg, &SH[buf * AB + c * 512]);
    }
    #pragma unroll
    for (int j = 0; j < 2; ++j){                 // B: 8 chunks, 2/wave
      const int c = wave * 2 + j;
      const int row = c * 16 + srow;
      gld16(B + (size_t)(tn + row) * K + kt * 32 + sg, &SH[BOFF + buf * 4096 + c * 512]);
    }
  };

  const int nkt = K >> 5;            // 12
  STAGE(0, 0);
  STAGE(1, 1);
  int b0 = 0;
  for (int kt = 0; kt < nkt; ++kt){
    if (kt + 1 < nkt){
      if (BM == 256) asm volatile("s_waitcnt vmcnt(6)" ::: "memory");
      else           asm volatile("s_waitcnt vmcnt(4)" ::: "memory");
    } else {
      asm volatile("s_waitcnt vmcnt(0)" ::: "memory");
    }
    __builtin_amdgcn_s_barrier();

    const u16* Ac = &SH[b0 * AB];
    const u16* Bc = &SH[BOFF + b0 * 4096];
    short8 af[4], bf[NN];
    #pragma unroll
    for (int i = 0; i < 4; ++i)
      af[i] = *(const short8*)&Ac[(wm + i * 16 + lrow) * 32 + ((g ^ key) << 3)];
    #pragma unroll
    for (int ni = 0; ni < NN; ++ni)
      bf[ni] = *(const short8*)&Bc[(wn + ni * 16 + lrow) * 32 + ((g ^ key) << 3)];

    asm volatile("s_waitcnt lgkmcnt(0)" ::: "memory");
    __builtin_amdgcn_sched_barrier(0);
    __builtin_amdgcn_s_barrier();

    const int bs = (b0 == 0) ? 2 : b0 - 1;       // (kt+2) % 3
    if (kt + 2 < nkt) STAGE(kt + 2, bs);

    __builtin_amdgcn_s_setprio(1);
    #pragma unroll
    for (int ni = 0; ni < NN; ++ni)
      #pragma unroll
      for (int mi = 0; mi < 4; ++mi)
        acc[mi][ni] = mfma16(af[mi], bf[ni], acc[mi][ni]);
    __builtin_amdgcn_s_setprio(0);

    b0 = (b0 == 2) ? 0 : b0 + 1;
  }

  // ---- epilogue (scalar, R6-measured). D: col=lane&15, row=(lane>>4)*4+reg.
  if (EPI == 1 && tn >= 768){
    // V third -> vt[b][h][d][t]; tm tile (256 rows) == one batch element
    const int bb = tm >> 8;
    #pragma unroll
    for (int ni = 0; ni < NN; ++ni){
      const int vcol0 = tn + wn - 768 + ni * 16;
      const int hh = vcol0 >> 6;
      const int dd = (vcol0 & 63) + lrow;
      const float bs = bias[tn + wn + ni * 16 + lrow];
      u16* vbase = Vt + ((size_t)(bb * 6 + hh) * 64 + dd) * 256;
      #pragma unroll
      for (int mi = 0; mi < 4; ++mi){
        #pragma unroll
        for (int r = 0; r < 4; ++r){
          const int t = wm + mi * 16 + g * 4 + r;
          vbase[t] = f2b(acc[mi][ni][r] + bs);
        }
      }
    }
  } else {
    #pragma unroll
    for (int mi = 0; mi < 4; ++mi){
      #pragma unroll
      for (int ni = 0; ni < NN; ++ni){
        const int gcol = tn + wn + ni * 16 + lrow;
        const float bs = bias[gcol];
        #pragma unroll
        for (int r = 0; r < 4; ++r){
          const int grow = tm + wm + mi * 16 + g * 4 + r;
          const float v = acc[mi][ni][r] + bs;
          if (EPI == 1) ((u16*)Cout)[(size_t)grow * CS + gcol] = f2b(v);
          else          ((float*)Cout)[(size_t)grow * CS + gcol] = v;
        }
      }
    }
  }
}

// ---------------------------------------------------------------------------
// Kernel 3: fused causal attention, one workgroup per (b,h), 4 waves.
// Swapped QK^T (S^T = K*Q^T): softmax lane-local(+2 shfl), P feeds PV from
// registers. K in LDS (XOR row swizzle). V^T PRE-TRANSPOSED from GEMM1.
// VALU diet: normalization DEFERRED to O. KEY FIX vs R13: the PV D-fragment
// puts O[q=g*4+r][d=lrow] in the lane, but lane-resident `sum` is for
// q=lrow (softmax mapping). Transport via __shfl(rs, g*4+r) -- sum for row q
// lives in every lane with (lane&15)==q; group-0 lane g*4+r supplies it.
// P converted to bf16 by truncation (P in [0,1], bias <= 2^-9 rel).
// q-tile->wave map {w, 15-w, w+4, 11-w}: exactly 34 causal tiles per wave.
// ---------------------------------------------------------------------------
__global__ __launch_bounds__(256) void attn_k(
    const u16* __restrict__ qkv, const u16* __restrict__ vt,
    u16* __restrict__ y)
{
  __shared__ u16 Klds[256 * 64];   // K rows (128B), 16B granules XOR'd by row&7
  __shared__ u16 Vlds[64 * 256];   // V^T rows d (512B): unit u at u^(d&7)
  const int tid  = threadIdx.x;
  const int lane = tid & 63;
  const int wave = tid >> 6;
  const int lrow = lane & 15;
  const int g    = lane >> 4;
  const int bh = blockIdx.x;
  const int b = bh / 6, h = bh % 6;
  const u16* qb  = qkv + (size_t)b * 256 * 768 + h * 64;
  const u16* kb  = qb + 384;
  const u16* vtb = vt + (size_t)(b * 6 + h) * 64 * 256;

  // ---- stage K: elem K[t][c16*8+e] -> Klds[t*64 + (c16^(t&7))*8 + e]
  #pragma unroll
  for (int j = 0; j < 8; ++j){
    const int c = wave * 8 + j;                 // 1KB chunk = 8 K-rows
    const int row = c * 8 + (lane >> 3);
    const int col = (((lane & 7) ^ (lane >> 3)) << 3);
    gld16(kb + (size_t)row * 768 + col, &Klds[c * 512]);
  }
  // ---- stage V^T: chunk c = rows {2c,2c+1}; LDS unit q of row d <- src q^(d&7)
  #pragma unroll
  for (int j = 0; j < 8; ++j){
    const int c  = wave * 8 + j;
    const int dd = c * 2 + (lane >> 5);
    const int q  = lane & 31;
    gld16(vtb + (size_t)dd * 256 + ((q ^ (dd & 7)) << 3), &Vlds[c * 512]);
  }
  __syncthreads();

  #pragma unroll
  for (int it = 0; it < 4; ++it){
    const int rb = (it == 0) ? wave : (it == 1) ? 15 - wave
                 : (it == 2) ? wave + 4 : 11 - wave;
    const int q0 = rb * 16;
    const u16* qrow = qb + (size_t)(q0 + lrow) * 768 + g * 8;
    const short8 qf0 = *(const short8*)(qrow);
    const short8 qf1 = *(const short8*)(qrow + 32);

    // S^T[t][q]: lane holds t = nt*16 + g*4 + r for its q = q0 + lrow
    float4v s[16];
    #pragma unroll
    for (int nt = 0; nt < 16; ++nt){
      if (nt <= rb){
        const int row = nt * 16 + lrow;    // K row (A operand m = lane&15)
        const int swk = lrow & 7;
        const short8 k0 = *(const short8*)&Klds[row * 64 + ((g ^ swk) << 3)];
        const short8 k1 = *(const short8*)&Klds[row * 64 + (((4 + g) ^ swk) << 3)];
        float4v a = (float4v){0.f, 0.f, 0.f, 0.f};
        a = mfma16(k0, qf0, a);
        a = mfma16(k1, qf1, a);
        if (nt == rb){                     // diagonal tile mask: t > q
          #pragma unroll
          for (int r = 0; r < 4; ++r)
            a[r] = (g * 4 + r > lrow) ? -1e30f : a[r];
        }
        s[nt] = a;
      }
    }

    // softmax (unnormalized): lane-local max/sum + reduce across 4 lane-groups
    float mx = -1e30f;
    #pragma unroll
    for (int nt = 0; nt < 16; ++nt) if (nt <= rb){
      #pragma unroll
      for (int r = 0; r < 4; ++r) mx = fmaxf(mx, s[nt][r]);
    }
    mx = fmaxf(mx, __shfl_xor(mx, 16));
    mx = fmaxf(mx, __shfl_xor(mx, 32));
    float sum = 0.f;
    #pragma unroll
    for (int nt = 0; nt < 16; ++nt) if (nt <= rb){
      #pragma unroll
      for (int r = 0; r < 4; ++r){
        const float p = exp2f((s[nt][r] - mx) * 0.18033688011112042f);
        s[nt][r] = p;
        sum += p;
      }
    }
    sum += __shfl_xor(sum, 16);
    sum += __shfl_xor(sum, 32);
    const float rs = 1.f / sum;            // rs for q = q0 + lrow
    // transport: O-epilogue lane needs rs for q = g*4+r (D-fragment mapping)
    float rsq[4];
    #pragma unroll
    for (int r = 0; r < 4; ++r) rsq[r] = __shfl(rs, g * 4 + r);

    // PV: O[q][d] += P[q][t] V[t][d]; slot map (both operands):
    //   i<4 -> t=kt*32+g*4+i ; i>=4 -> t=kt*32+16+g*4+(i-4)
    float4v o0 = (float4v){0,0,0,0}, o1 = (float4v){0,0,0,0};
    float4v o2 = (float4v){0,0,0,0}, o3 = (float4v){0,0,0,0};
    const int swk = lrow & 7;
    #pragma unroll
    for (int kt = 0; kt < 8; ++kt){
      if (2 * kt <= rb){
        short8 pa;
        #pragma unroll
        for (int r = 0; r < 4; ++r) pa[r] = (short)f2b_t(s[2 * kt][r]);
        if (2 * kt + 1 <= rb){
          #pragma unroll
          for (int r = 0; r < 4; ++r) pa[4 + r] = (short)f2b_t(s[2 * kt + 1][r]);
        } else {
          #pragma unroll
          for (int r = 0; r < 4; ++r) pa[4 + r] = 0;
        }
        // granule p of row d at elems: d*256 + ((p>>1)^(d&7))*8 + (p&1)*4
        const int plo_e = (((kt * 4 +     (g >> 1)) ^ swk) << 3) + ((g & 1) << 2);
        const int phi_e = (((kt * 4 + 2 + (g >> 1)) ^ swk) << 3) + ((g & 1) << 2);
        #pragma unroll
        for (int dt = 0; dt < 4; ++dt){
          const u16* vrow = &Vlds[(size_t)(dt * 16 + lrow) * 256];
          const short4v vlo = *(const short4v*)&vrow[plo_e];
          const short4v vhi = *(const short4v*)&vrow[phi_e];
          const short8 bf = __builtin_shufflevector(vlo, vhi, 0,1,2,3,4,5,6,7);
          if      (dt == 0) o0 = mfma16(pa, bf, o0);
          else if (dt == 1) o1 = mfma16(pa, bf, o1);
          else if (dt == 2) o2 = mfma16(pa, bf, o2);
          else              o3 = mfma16(pa, bf, o3);
        }
      }
    }

    // write O (normalize with TRANSPORTED rs): row q = g*4+r, col d = lrow
    u16* yb = y + (size_t)(b * 256 + q0) * 384 + h * 64;
    #pragma unroll
    for (int r = 0; r < 4; ++r){
      const int q = g * 4 + r;
      yb[(size_t)q * 384 +  0 + lrow] = f2b(o0[r] * rsq[r]);
      yb[(size_t)q * 384 + 16 + lrow] = f2b(o1[r] * rsq[r]);
      yb[(size_t)q * 384 + 32 + lrow] = f2b(o2[r] * rsq[r]);
      yb[(size_t)q * 384 + 48 + lrow] = f2b(o3[r] * rsq[r]);
    }
  }
}

// ---------------------------------------------------------------------------
extern "C" void kernel_launch(void* const* d_in, const int* in_sizes, int n_in,
                              void* d_out, int out_size, void* d_ws, size_t ws_size,
                              hipStream_t stream)
{
  const float* x      = (const float*)d_in[0];
  const float* w_attn = (const float*)d_in[1];
  const float* b_attn = (const float*)d_in[2];
  const float* w_proj = (const float*)d_in[3];
  const float* b_proj = (const float*)d_in[4];
  float* out = (float*)d_out;

  // workspace layout (bytes)
  char* ws = (char*)d_ws;
  u16* xb  = (u16*)(ws);                 // 25,165,824  x bf16 [32768,384]
  u16* wab = (u16*)(ws + 25165824);      //    884,736  w_attn bf16 [1152,384]
  u16* wpb = (u16*)(ws + 26050560);      //    294,912  w_proj bf16 [384,384]
  u16* qkv = (u16*)(ws + 26345472);      // 50,331,648  q,k bf16 [32768,768]
  u16* vt  = (u16*)(ws + 76677120);      // 25,165,824  V^T bf16 [128][6][64][256]
  u16* yb  = (u16*)(ws + 101842944);     // 25,165,824  attn out bf16 [32768,384]
  if (ws_size < 127008768) return;

  cvt3<<<2048, 256, 0, stream>>>(x, xb, 3145728,
                                 w_attn, wab, 110592,
                                 w_proj, wpb, 36864);
  // GEMM1: BM=256 -> 128 M-tiles x 9 N-tiles = 1152 blocks (XCD-chunked)
  gemm_k<256,1><<<1152, 256, 0, stream>>>(xb, wab, b_attn, qkv, vt, 32768, 1152, 384, 768);
  attn_k<<<768, 256, 0, stream>>>(qkv, vt, yb);
  // GEMM2: BM=128 -> 256 M-tiles x 3 N-tiles = 768 blocks, 3 resident/CU
  gemm_k<128,0><<<768, 256, 0, stream>>>(yb, wpb, b_proj, out, nullptr, 32768, 384, 384, 384);
}